// Round 3
// baseline (187.438 us; speedup 1.0000x reference)
//
#include <hip/hip_runtime.h>
#include <hip/hip_bf16.h>
#include <stdint.h>

typedef __attribute__((ext_vector_type(8))) short bf16x8;
typedef __attribute__((ext_vector_type(4))) float f32x4;

#define N_IMG 32
#define CIN 128
#define COUT 256
#define HH 56
#define HW (HH*HH)            // 3136
#define HP 58
#define PXTOT (N_IMG*HW)      // 100352

// ws layout (bytes)
#define XP_BYTES    27557888u   // 32*58*58*128*2
#define WT_BYTES    589824u     // 36*256*32*2
#define INV_BYTES   12544u
#define STATS_BYTES 2048u
#define SS_BYTES    2048u
#define Y_BYTES     51380224u   // 256*100352*2

__device__ __forceinline__ unsigned short f2bf(float f) {
  unsigned int u = __builtin_bit_cast(unsigned int, f);
  unsigned int r = u + 0x7FFFu + ((u >> 16) & 1u);
  return (unsigned short)(r >> 16);
}

__device__ __forceinline__ float bf2f(unsigned short s) {
  return __builtin_bit_cast(float, (unsigned int)s << 16);
}

__device__ __forceinline__ void gload_lds16(const void* g, void* l) {
  __builtin_amdgcn_global_load_lds((const __attribute__((address_space(1))) void*)g,
                                   (__attribute__((address_space(3))) void*)l, 16, 0, 0);
}

__global__ void invperm_kernel(const int* __restrict__ perm, int* __restrict__ inv) {
  int i = blockIdx.x * 256 + threadIdx.x;
  if (i < HW) inv[perm[i]] = i;
}

// weight relayout: wt[kk][co][32] bf16, kk = o*4+cb (o=3*dh+dw, cb = c-block of 32)
__global__ void wcvt_kernel(const float* __restrict__ w, unsigned short* __restrict__ wt) {
  int i = blockIdx.x * 256 + threadIdx.x;     // 0..294911 dst index
  if (i >= 36 * COUT * 32) return;
  int kk = i >> 13;
  int r = i & 8191;
  int co = r >> 5, cl = r & 31;
  int o = kk >> 2, cb = kk & 3;
  int c = cb * 32 + cl;
  int dh = o / 3, dw = o % 3;
  wt[i] = f2bf(w[((co * CIN + c) * 3 + dh) * 3 + dw]);
}

// permute+pad+bf16-cast x -> xp NHWC [32][58][58][128]
__global__ __launch_bounds__(256) void pad_perm_kernel(const float* __restrict__ x,
                                                       const int* __restrict__ inv,
                                                       unsigned short* __restrict__ xp) {
  __shared__ unsigned short T[64 * 128];
  __shared__ int dest_off[64];
  int b = blockIdx.x;            // 0..1567
  int n = b / 49;
  int s0 = (b % 49) * 64;
  int t = threadIdx.x;

  if (t < 64) {
    int s = inv[s0 + t];
    int h = s / HH, w = s % HH;
    dest_off[t] = ((n * HP + h + 1) * HP + (w + 1)) * CIN;
  }
  const float* xplane = x + (size_t)n * CIN * HW;
  #pragma unroll
  for (int i = 0; i < 32; ++i) {
    int idx = i * 256 + t;
    int c = idx >> 6, j = idx & 63;
    float v = xplane[c * HW + s0 + j];
    int byte = j * 256 + ((2 * c) ^ ((j & 7) << 4));
    *(unsigned short*)((char*)T + byte) = f2bf(v);
  }
  __syncthreads();
  #pragma unroll
  for (int i = 0; i < 4; ++i) {
    int u = i * 256 + t;
    int j = u >> 4, chunk = u & 15;
    int byte = j * 256 + ((chunk * 16) ^ ((j & 7) << 4));
    bf16x8 v = *(const bf16x8*)((const char*)T + byte);
    *(bf16x8*)(xp + dest_off[j] + chunk * 8) = v;
  }
}

// Implicit GEMM conv, 128co x 128px tile, BK=32, double-buffered prefetch,
// fused BN-stats epilogue. YMODE 1: y -> bf16 [co][px] ws; 0: y -> fp32 NCHW.
template<int YMODE>
__global__ __launch_bounds__(256) void conv_kernel(const unsigned short* __restrict__ xp,
                                                   const unsigned short* __restrict__ wt,
                                                   unsigned short* __restrict__ ybf,
                                                   float* __restrict__ yf32,
                                                   float* __restrict__ stats) {
  __shared__ __align__(16) unsigned short A_lds[2][128 * 32];
  __shared__ __align__(16) unsigned short B_lds[2][128 * 32];
  int phys = blockIdx.x;
  int b = (phys & 7) * 196 + (phys >> 3);   // XCD swizzle (1568 = 8*196, bijective)
  int coT = b & 1;
  int pT = b >> 1;
  int t = threadIdx.x;
  int lane = t & 63;
  int wid = t >> 6;
  int wm = wid >> 1, wn = wid & 1;

  int p0 = pT * 128;
  long bsrc[2];
  #pragma unroll
  for (int i = 0; i < 2; ++i) {
    int p = i * 64 + (t >> 2);
    int flat = p0 + p;
    int n = flat / HW, s = flat % HW;
    int h = s / HH, w = s % HH;
    bsrc[i] = (long)((n * HP + h) * HP + w) * CIN + (t & 3) * 8;
  }
  // A source: wt[kk*8192 + (coT*128 + row)*32 + chunk], row = t>>2 (+64 for issue 1)
  const unsigned short* a0 = wt + (coT * 128 + (t >> 2)) * 32 + (t & 3) * 8;

  f32x4 acc[4][4];
  #pragma unroll
  for (int m = 0; m < 4; ++m)
    #pragma unroll
    for (int q = 0; q < 4; ++q) acc[m][q] = (f32x4)0.f;

  auto stage = [&](int kk, int buf) {
    const unsigned short* as = a0 + kk * 8192;
    gload_lds16(as,        &A_lds[buf][t * 8]);
    gload_lds16(as + 2048, &A_lds[buf][2048 + t * 8]);
    int o = kk >> 2, cb = kk & 3;
    int boff = ((o / 3) * HP + (o % 3)) * CIN + cb * 32;
    gload_lds16(xp + bsrc[0] + boff, &B_lds[buf][t * 8]);
    gload_lds16(xp + bsrc[1] + boff, &B_lds[buf][2048 + t * 8]);
  };

  stage(0, 0);
  __syncthreads();

  for (int kk = 0; kk < 36; ++kk) {
    int cur = kk & 1;
    if (kk < 35) stage(kk + 1, cur ^ 1);   // prefetch overlaps with compute below

    bf16x8 af[4], bfr[4];
    int krow = (lane >> 4) * 8;
    #pragma unroll
    for (int m = 0; m < 4; ++m)
      af[m] = *(const bf16x8*)&A_lds[cur][(wm * 64 + m * 16 + (lane & 15)) * 32 + krow];
    #pragma unroll
    for (int q = 0; q < 4; ++q)
      bfr[q] = *(const bf16x8*)&B_lds[cur][(wn * 64 + q * 16 + (lane & 15)) * 32 + krow];
    #pragma unroll
    for (int m = 0; m < 4; ++m)
      #pragma unroll
      for (int q = 0; q < 4; ++q)
        acc[m][q] = __builtin_amdgcn_mfma_f32_16x16x32_bf16(af[m], bfr[q], acc[m][q], 0, 0, 0);

    __syncthreads();   // drains vmcnt (prefetch done) + guards LDS reuse
  }

  // ---- fused BN partial stats (from fp32 acc) ----
  float ps1[4][4], ps2[4][4];
  #pragma unroll
  for (int m = 0; m < 4; ++m)
    #pragma unroll
    for (int j = 0; j < 4; ++j) {
      float a = 0.f, bb = 0.f;
      #pragma unroll
      for (int q = 0; q < 4; ++q) { float v = acc[m][q][j]; a += v; bb += v * v; }
      ps1[m][j] = a; ps2[m][j] = bb;
    }
  #pragma unroll
  for (int off = 1; off < 16; off <<= 1) {
    #pragma unroll
    for (int m = 0; m < 4; ++m)
      #pragma unroll
      for (int j = 0; j < 4; ++j) {
        ps1[m][j] += __shfl_xor(ps1[m][j], off, 64);
        ps2[m][j] += __shfl_xor(ps2[m][j], off, 64);
      }
  }

  // ---- y store ----
  #pragma unroll
  for (int q = 0; q < 4; ++q) {
    int px = p0 + wn * 64 + q * 16 + (lane & 15);
    if (YMODE == 1) {
      #pragma unroll
      for (int m = 0; m < 4; ++m) {
        int co = coT * 128 + wm * 64 + m * 16 + ((lane >> 4) * 4);
        #pragma unroll
        for (int j = 0; j < 4; ++j)
          ybf[(size_t)(co + j) * PXTOT + px] = f2bf(acc[m][q][j]);
      }
    } else {
      int nimg = px / HW, s = px % HW;
      float* obase = yf32 + (size_t)nimg * COUT * HW + s;
      #pragma unroll
      for (int m = 0; m < 4; ++m) {
        int co = coT * 128 + wm * 64 + m * 16 + ((lane >> 4) * 4);
        #pragma unroll
        for (int j = 0; j < 4; ++j)
          obase[(size_t)(co + j) * HW] = acc[m][q][j];
      }
    }
  }

  // ---- combine stats across waves in LDS, then atomics ----
  float* sbuf = (float*)&A_lds[0][0];   // 512 floats: s1[128][2], s2[128][2]
  if ((lane & 15) == 0) {
    int g = lane >> 4;
    #pragma unroll
    for (int m = 0; m < 4; ++m)
      #pragma unroll
      for (int j = 0; j < 4; ++j) {
        int idx = wm * 64 + m * 16 + g * 4 + j;
        sbuf[idx * 2 + wn] = ps1[m][j];
        sbuf[256 + idx * 2 + wn] = ps2[m][j];
      }
  }
  __syncthreads();
  if (t < 128) {
    int co = coT * 128 + t;
    atomicAdd(&stats[co],       sbuf[t * 2] + sbuf[t * 2 + 1]);
    atomicAdd(&stats[256 + co], sbuf[256 + t * 2] + sbuf[256 + t * 2 + 1]);
  }
}

__global__ void bnparam_kernel(const float* __restrict__ stats,
                               const float* __restrict__ gamma,
                               const float* __restrict__ beta,
                               float* __restrict__ ss) {
  int c = threadIdx.x;  // 256
  float cnt = (float)(N_IMG * HW);
  float mean = stats[c] / cnt;
  float var = stats[256 + c] / cnt - mean * mean;
  float sc = gamma[c] * rsqrtf(var + 1e-5f);
  ss[c] = sc;
  ss[256 + c] = beta[c] - mean * sc;
}

// y bf16 [co][px] -> out fp32 NCHW, BN+ReLU
__global__ __launch_bounds__(256) void bnrelu_bf16_kernel(const unsigned short* __restrict__ y,
                                                          const float* __restrict__ ss,
                                                          float* __restrict__ out) {
  int idx = blockIdx.x * 256 + threadIdx.x;   // 8-px unit; grid exact
  const int UN = PXTOT / 8;                    // 12544
  int co = idx / UN;
  int rem = idx - co * UN;
  float sc = ss[co], sh = ss[256 + co];
  bf16x8 v = *(const bf16x8*)(y + (size_t)co * PXTOT + rem * 8);
  int px0 = rem * 8;
  int n = px0 / HW, s = px0 - n * HW;
  float* o = out + ((size_t)n * COUT + co) * HW + s;
  float4 r0, r1;
  r0.x = fmaxf(bf2f((unsigned short)v[0]) * sc + sh, 0.f);
  r0.y = fmaxf(bf2f((unsigned short)v[1]) * sc + sh, 0.f);
  r0.z = fmaxf(bf2f((unsigned short)v[2]) * sc + sh, 0.f);
  r0.w = fmaxf(bf2f((unsigned short)v[3]) * sc + sh, 0.f);
  r1.x = fmaxf(bf2f((unsigned short)v[4]) * sc + sh, 0.f);
  r1.y = fmaxf(bf2f((unsigned short)v[5]) * sc + sh, 0.f);
  r1.z = fmaxf(bf2f((unsigned short)v[6]) * sc + sh, 0.f);
  r1.w = fmaxf(bf2f((unsigned short)v[7]) * sc + sh, 0.f);
  ((float4*)o)[0] = r0;
  ((float4*)o)[1] = r1;
}

// fallback: in-place BN+ReLU on fp32 NCHW y in d_out
__global__ __launch_bounds__(256) void bnrelu_inplace_kernel(float* __restrict__ y,
                                                             const float* __restrict__ ss) {
  int idx = blockIdx.x * 256 + threadIdx.x;
  if (idx >= (N_IMG * COUT * HW) / 4) return;
  int plane = idx / (HW / 4);
  int co = plane & 255;
  float sc = ss[co], sh = ss[256 + co];
  float4 v = ((float4*)y)[idx];
  v.x = fmaxf(v.x * sc + sh, 0.f);
  v.y = fmaxf(v.y * sc + sh, 0.f);
  v.z = fmaxf(v.z * sc + sh, 0.f);
  v.w = fmaxf(v.w * sc + sh, 0.f);
  ((float4*)y)[idx] = v;
}

extern "C" void kernel_launch(void* const* d_in, const int* in_sizes, int n_in,
                              void* d_out, int out_size, void* d_ws, size_t ws_size,
                              hipStream_t stream) {
  const float* x     = (const float*)d_in[0];
  const float* w     = (const float*)d_in[1];
  const float* gamma = (const float*)d_in[2];
  const float* beta  = (const float*)d_in[3];
  const int*   perm  = (const int*)d_in[4];
  float* out = (float*)d_out;
  char* ws = (char*)d_ws;

  unsigned short* xp = (unsigned short*)ws;
  unsigned short* wt = (unsigned short*)(ws + XP_BYTES);
  int* inv           = (int*)(ws + XP_BYTES + WT_BYTES);
  float* stats       = (float*)(ws + XP_BYTES + WT_BYTES + INV_BYTES);
  float* ss          = (float*)(ws + XP_BYTES + WT_BYTES + INV_BYTES + STATS_BYTES);
  unsigned short* y  = (unsigned short*)(ws + XP_BYTES + WT_BYTES + INV_BYTES + STATS_BYTES + SS_BYTES);
  size_t need_y = (size_t)XP_BYTES + WT_BYTES + INV_BYTES + STATS_BYTES + SS_BYTES + Y_BYTES;
  bool ymode = ws_size >= need_y;

  hipMemsetAsync(xp, 0, XP_BYTES, stream);
  hipMemsetAsync(stats, 0, STATS_BYTES, stream);

  invperm_kernel<<<(HW + 255) / 256, 256, 0, stream>>>(perm, inv);
  wcvt_kernel<<<(36 * COUT * 32 + 255) / 256, 256, 0, stream>>>(w, wt);
  pad_perm_kernel<<<N_IMG * 49, 256, 0, stream>>>(x, inv, xp);
  if (ymode) {
    conv_kernel<1><<<1568, 256, 0, stream>>>(xp, wt, y, out, stats);
    bnparam_kernel<<<1, 256, 0, stream>>>(stats, gamma, beta, ss);
    bnrelu_bf16_kernel<<<COUT * (PXTOT / 8) / 256, 256, 0, stream>>>(y, ss, out);
  } else {
    conv_kernel<0><<<1568, 256, 0, stream>>>(xp, wt, (unsigned short*)out, out, stats);
    bnparam_kernel<<<1, 256, 0, stream>>>(stats, gamma, beta, ss);
    bnrelu_inplace_kernel<<<(N_IMG * COUT * HW / 4 + 255) / 256, 256, 0, stream>>>(out, ss);
  }
}

// Round 4
// 133.020 us; speedup vs baseline: 1.4091x; 1.4091x over previous
//
#include <hip/hip_runtime.h>
#include <hip/hip_bf16.h>
#include <stdint.h>

typedef __attribute__((ext_vector_type(8))) short bf16x8;
typedef __attribute__((ext_vector_type(4))) float f32x4;

#define N_IMG 32
#define CIN 128
#define COUT 256
#define HH 56
#define HW (HH*HH)            // 3136
#define HP 58
#define PXTOT (N_IMG*HW)      // 100352
#define NKT 18                // K tiles of 64 (9 offsets x 2)

// ws layout (bytes)
#define XP_BYTES    27557888u   // 32*58*58*128*2
#define WT_BYTES    589824u     // 18*256*64*2
#define INV_BYTES   12544u
#define STATS_BYTES 2048u
#define WS_MIN      (XP_BYTES + WT_BYTES + INV_BYTES + STATS_BYTES)
#define Y_BYTES     51380224u   // 256*100352*2

__device__ __forceinline__ unsigned short f2bf(float f) {
  unsigned int u = __builtin_bit_cast(unsigned int, f);
  unsigned int r = u + 0x7FFFu + ((u >> 16) & 1u);
  return (unsigned short)(r >> 16);
}
__device__ __forceinline__ float bf2f(unsigned short s) {
  return __builtin_bit_cast(float, (unsigned int)s << 16);
}
__device__ __forceinline__ void gload_lds16(const void* g, void* l) {
  __builtin_amdgcn_global_load_lds((const __attribute__((address_space(1))) void*)g,
                                   (__attribute__((address_space(3))) void*)l, 16, 0, 0);
}

#define BAR()    __builtin_amdgcn_s_barrier()
#define WAITV6() asm volatile("s_waitcnt vmcnt(6)" ::: "memory")
#define WAITV0() asm volatile("s_waitcnt vmcnt(0)" ::: "memory")
#define WAITL()  asm volatile("s_waitcnt lgkmcnt(0)" ::: "memory")
#define SCHEDB() __builtin_amdgcn_sched_barrier(0)

// weights relayout wt[kt][co][64] (kt = o*2+ch), + inverse perm, + stats zero
__global__ __launch_bounds__(256) void wcvt_kernel(const float* __restrict__ w,
                                                   unsigned short* __restrict__ wt,
                                                   const int* __restrict__ perm,
                                                   int* __restrict__ inv,
                                                   float* __restrict__ stats) {
  int i = blockIdx.x * 256 + threadIdx.x;     // 0..294911
  if (i < HW) inv[perm[i]] = i;
  if (i < 512) stats[i] = 0.f;
  if (i >= NKT * COUT * 64) return;
  int kt = i >> 14;
  int co = (i >> 6) & 255;
  int cl = i & 63;
  int o = kt >> 1, ch = kt & 1;
  int c = ch * 64 + cl;
  wt[i] = f2bf(w[(co * CIN + c) * 9 + o]);
}

// permute+pad+bf16 x -> xp NHWC [32][58][58][128]; also zeros the pad ring
__global__ __launch_bounds__(256) void pad_perm_kernel(const float* __restrict__ x,
                                                       const int* __restrict__ inv,
                                                       unsigned short* __restrict__ xp) {
  __shared__ unsigned short T[64 * 128];
  __shared__ int dest_off[64];
  int b = blockIdx.x;            // 0..1567
  int n = b / 49;
  int k = b % 49;
  int s0 = k * 64;
  int t = threadIdx.x;

  // zero pad ring: 228 pad-pixels/image, 5 per block, 32 threads (8B) each
  if (t < 160) {
    int pi = k * 5 + (t >> 5);
    if (pi < 228) {
      int h, w2;
      if (pi < 58)       { h = 0;            w2 = pi; }
      else if (pi < 116) { h = 57;           w2 = pi - 58; }
      else if (pi < 172) { h = pi - 116 + 1; w2 = 0; }
      else               { h = pi - 172 + 1; w2 = 57; }
      uint2 z = {0u, 0u};
      *(uint2*)(xp + (size_t)((n * HP + h) * HP + w2) * CIN + (t & 31) * 4) = z;
    }
  }

  if (t < 64) {
    int s = inv[s0 + t];
    int h = s / HH, w = s % HH;
    dest_off[t] = ((n * HP + h + 1) * HP + (w + 1)) * CIN;
  }
  const float* xplane = x + (size_t)n * CIN * HW;
  #pragma unroll
  for (int i = 0; i < 32; ++i) {
    int idx = i * 256 + t;
    int c = idx >> 6, j = idx & 63;
    float v = xplane[c * HW + s0 + j];
    int byte = j * 256 + ((2 * c) ^ ((j & 7) << 4));
    *(unsigned short*)((char*)T + byte) = f2bf(v);
  }
  __syncthreads();
  #pragma unroll
  for (int i = 0; i < 4; ++i) {
    int u = i * 256 + t;
    int j = u >> 4, chunk = u & 15;
    int byte = j * 256 + ((chunk * 16) ^ ((j & 7) << 4));
    bf16x8 v = *(const bf16x8*)((const char*)T + byte);
    *(bf16x8*)(xp + dest_off[j] + chunk * 8) = v;
  }
}

// ---- 8-phase implicit-GEMM conv (m201 template port) ----
// BM=256(co) x BN=256(px), BK=64, 512 thr (8 waves 2x4), LDS 128KB dbuf.
// A LDS rows: r = mh*128 + wm*64 + q  <->  co = wm*128 + mh*64 + q
// B LDS rows: r = h*128 + wn*32 + q   <->  px = wn*64 + h*32 + q
// swizzle: 16B-chunk ^= (row & 7), applied on pre-swizzled global src + ds_read
template<int YMODE>
__global__ __launch_bounds__(512, 2) void conv8_kernel(const unsigned short* __restrict__ xp,
                                                       const unsigned short* __restrict__ wt,
                                                       unsigned short* __restrict__ ybf,
                                                       float* __restrict__ yf32,
                                                       float* __restrict__ stats) {
  extern __shared__ unsigned short lds[];   // 65536 shorts: buf[2] x (A 16384 | B 16384)
  int t = threadIdx.x;
  int lane = t & 63, wid = t >> 6;
  int wm = wid >> 2, wn = wid & 3;
  int l = lane & 15, g = lane >> 4;
  int phys = blockIdx.x;
  int b = (phys & 7) * 49 + (phys >> 3);    // XCD swizzle (392 = 8*49)
  int p0 = b * 256;

  // ---- staging precomputes (per-thread slots u = t, t+512) ----
  int aoffA[2];
  int bsrcB[2][2];   // [h][i]
  #pragma unroll
  for (int i = 0; i < 2; ++i) {
    int u = t + i * 512;
    int clog = (u & 7) ^ ((u >> 3) & 7);
    aoffA[i] = (((u >> 9) & 1) * 128 + ((u >> 3) & 63)) * 64 + clog * 8;
    int r = u >> 3;                         // 0..127
    #pragma unroll
    for (int h = 0; h < 2; ++h) {
      int pxl = ((r >> 5) << 6) + h * 32 + (r & 31);
      int px = p0 + pxl;
      int n = px / HW, s = px % HW;
      int hi = s / HH, wi = s % HH;
      bsrcB[h][i] = ((n * HP + hi) * HP + wi) * CIN + clog * 8;
    }
  }

  auto stageA = [&](int kt, int h) {
    unsigned short* d = lds + (kt & 1) * 32768 + h * 8192 + t * 8;
    const unsigned short* s0 = wt + kt * 16384 + h * 4096;
    gload_lds16(s0 + aoffA[0], d);
    gload_lds16(s0 + aoffA[1], d + 4096);
  };
  auto stageB = [&](int kt, int h) {
    int o = kt >> 1;
    int koff = ((o / 3) * HP + (o % 3)) * CIN + (kt & 1) * 64;
    unsigned short* d = lds + (kt & 1) * 32768 + 16384 + h * 8192 + t * 8;
    gload_lds16(xp + bsrcB[h][0] + koff, d);
    gload_lds16(xp + bsrcB[h][1] + koff, d + 4096);
  };

  // ---- ds_read precomputes ----
  int arow0 = (wm * 64 + l) * 64;
  int browb = (wn * 32 + l) * 64;
  int xorc = l & 7;
  int pc0 = (g ^ xorc) * 8;
  int pc1 = ((4 + g) ^ xorc) * 8;

  bf16x8 af[4][2], bf[4][2];
  f32x4 acc[8][4];
  #pragma unroll
  for (int m = 0; m < 8; ++m)
    #pragma unroll
    for (int n = 0; n < 4; ++n) acc[m][n] = (f32x4)0.f;

#define LDA(MH) { _Pragma("unroll") for (int mm = 0; mm < 4; ++mm) { \
    af[mm][0] = *(const bf16x8*)(cur + arow0 + (MH)*8192 + mm*1024 + pc0); \
    af[mm][1] = *(const bf16x8*)(cur + arow0 + (MH)*8192 + mm*1024 + pc1); } }
#define LDB(NH) { _Pragma("unroll") for (int nn = 0; nn < 2; ++nn) { \
    bf[(NH)*2+nn][0] = *(const bf16x8*)(cur + 16384 + (NH)*8192 + browb + nn*1024 + pc0); \
    bf[(NH)*2+nn][1] = *(const bf16x8*)(cur + 16384 + (NH)*8192 + browb + nn*1024 + pc1); } }
#define MFMA_Q(MB, NB) { _Pragma("unroll") for (int mm = 0; mm < 4; ++mm) \
    _Pragma("unroll") for (int nn = 0; nn < 2; ++nn) { \
      acc[(MB)+mm][(NB)+nn] = __builtin_amdgcn_mfma_f32_16x16x32_bf16(af[mm][0], bf[(NB)+nn][0], acc[(MB)+mm][(NB)+nn], 0, 0, 0); \
      acc[(MB)+mm][(NB)+nn] = __builtin_amdgcn_mfma_f32_16x16x32_bf16(af[mm][1], bf[(NB)+nn][1], acc[(MB)+mm][(NB)+nn], 0, 0, 0); } }

  // ---- prologue: t0 all 4 halves, t1 {Ah0,Bh0,Bh1}; t1.Ah1 comes at (0,P0) ----
  stageA(0, 0); stageA(0, 1); stageB(0, 0); stageB(0, 1);
  stageA(1, 0); stageB(1, 0); stageB(1, 1);
  WAITV6();
  BAR();

  for (int kt = 0; kt < NKT; ++kt) {
    const unsigned short* cur = lds + (kt & 1) * 32768;
    bool st1 = (kt + 1) < NKT;
    bool st2 = (kt + 2) < NKT;
    // ---- P0: read af(mh0), bf(n01); stage (t+1).Ah1 ----
    LDA(0); LDB(0);
    if (st1) stageA(kt + 1, 1);
    BAR();
    WAITL(); SCHEDB();
    __builtin_amdgcn_s_setprio(1);
    MFMA_Q(0, 0);
    __builtin_amdgcn_s_setprio(0);
    BAR();
    // ---- P1: read bf(n23); stage (t+2).Ah0 ----
    LDB(1);
    if (st2) stageA(kt + 2, 0);
    BAR();
    WAITL(); SCHEDB();
    __builtin_amdgcn_s_setprio(1);
    MFMA_Q(0, 2);
    __builtin_amdgcn_s_setprio(0);
    BAR();
    // ---- P2: read af(mh1); stage (t+2).Bh0 ----
    LDA(1);
    if (st2) stageB(kt + 2, 0);
    BAR();
    WAITL(); SCHEDB();
    __builtin_amdgcn_s_setprio(1);
    MFMA_Q(4, 2);
    __builtin_amdgcn_s_setprio(0);
    BAR();
    // ---- P3: stage (t+2).Bh1; MFMA; counted vmcnt at tile boundary ----
    if (st2) stageB(kt + 2, 1);
    BAR();
    __builtin_amdgcn_s_setprio(1);
    MFMA_Q(4, 0);
    __builtin_amdgcn_s_setprio(0);
    if (st2) { WAITV6(); } else if (kt == NKT - 2) { WAITV0(); }
    BAR();
  }
#undef LDA
#undef LDB
#undef MFMA_Q

  // ---- fused BN partial stats ----
  float ps1[8][4], ps2[8][4];
  #pragma unroll
  for (int m = 0; m < 8; ++m)
    #pragma unroll
    for (int j = 0; j < 4; ++j) {
      float a = 0.f, b2 = 0.f;
      #pragma unroll
      for (int n = 0; n < 4; ++n) { float v = acc[m][n][j]; a += v; b2 += v * v; }
      #pragma unroll
      for (int off = 1; off < 16; off <<= 1) {
        a  += __shfl_xor(a, off, 64);
        b2 += __shfl_xor(b2, off, 64);
      }
      ps1[m][j] = a; ps2[m][j] = b2;
    }

  // ---- y store ----
  #pragma unroll
  for (int n = 0; n < 4; ++n) {
    int px = p0 + wn * 64 + n * 16 + l;
    if (YMODE == 1) {
      #pragma unroll
      for (int m = 0; m < 8; ++m) {
        int co = wm * 128 + m * 16 + g * 4;
        #pragma unroll
        for (int j = 0; j < 4; ++j)
          ybf[(size_t)(co + j) * PXTOT + px] = f2bf(acc[m][n][j]);
      }
    } else {
      int nimg = px / HW, s = px % HW;
      float* obase = yf32 + (size_t)nimg * COUT * HW + s;
      #pragma unroll
      for (int m = 0; m < 8; ++m) {
        int co = wm * 128 + m * 16 + g * 4;
        #pragma unroll
        for (int j = 0; j < 4; ++j)
          obase[(size_t)(co + j) * HW] = acc[m][n][j];
      }
    }
  }

  // ---- combine stats in LDS, one atomic pair per co ----
  float* sb = (float*)lds;   // s1[256][4], s2[256][4]
  if (l == 0) {
    #pragma unroll
    for (int m = 0; m < 8; ++m)
      #pragma unroll
      for (int j = 0; j < 4; ++j) {
        int co = wm * 128 + m * 16 + g * 4 + j;
        sb[co * 4 + wn] = ps1[m][j];
        sb[1024 + co * 4 + wn] = ps2[m][j];
      }
  }
  BAR();
  if (t < 256) {
    float a  = sb[t * 4] + sb[t * 4 + 1] + sb[t * 4 + 2] + sb[t * 4 + 3];
    float b2 = sb[1024 + t * 4] + sb[1024 + t * 4 + 1] + sb[1024 + t * 4 + 2] + sb[1024 + t * 4 + 3];
    atomicAdd(&stats[t], a);
    atomicAdd(&stats[256 + t], b2);
  }
}

// y bf16 [co][px] -> out fp32 NCHW, BN(params folded)+ReLU
__global__ __launch_bounds__(256) void bnrelu1_kernel(const unsigned short* __restrict__ y,
                                                      const float* __restrict__ stats,
                                                      const float* __restrict__ gamma,
                                                      const float* __restrict__ beta,
                                                      float* __restrict__ out) {
  int idx = blockIdx.x * 256 + threadIdx.x;   // 8-px units
  const int UN = PXTOT / 8;                   // 12544
  int co = idx / UN;
  int rem = idx - co * UN;
  float cnt = (float)PXTOT;
  float mean = stats[co] / cnt;
  float var = stats[256 + co] / cnt - mean * mean;
  float sc = gamma[co] * rsqrtf(var + 1e-5f);
  float sh = beta[co] - mean * sc;
  bf16x8 v = *(const bf16x8*)(y + (size_t)co * PXTOT + rem * 8);
  int px0 = rem * 8;
  int n = px0 / HW, s = px0 - n * HW;
  float* o = out + ((size_t)n * COUT + co) * HW + s;
  float4 r0, r1;
  r0.x = fmaxf(bf2f((unsigned short)v[0]) * sc + sh, 0.f);
  r0.y = fmaxf(bf2f((unsigned short)v[1]) * sc + sh, 0.f);
  r0.z = fmaxf(bf2f((unsigned short)v[2]) * sc + sh, 0.f);
  r0.w = fmaxf(bf2f((unsigned short)v[3]) * sc + sh, 0.f);
  r1.x = fmaxf(bf2f((unsigned short)v[4]) * sc + sh, 0.f);
  r1.y = fmaxf(bf2f((unsigned short)v[5]) * sc + sh, 0.f);
  r1.z = fmaxf(bf2f((unsigned short)v[6]) * sc + sh, 0.f);
  r1.w = fmaxf(bf2f((unsigned short)v[7]) * sc + sh, 0.f);
  ((float4*)o)[0] = r0;
  ((float4*)o)[1] = r1;
}

// fallback: in-place BN(folded)+ReLU on fp32 NCHW in d_out
__global__ __launch_bounds__(256) void bnrelu0_kernel(float* __restrict__ y,
                                                      const float* __restrict__ stats,
                                                      const float* __restrict__ gamma,
                                                      const float* __restrict__ beta) {
  int idx = blockIdx.x * 256 + threadIdx.x;   // float4 units, grid exact
  int plane = idx / (HW / 4);
  int co = plane & 255;
  float cnt = (float)PXTOT;
  float mean = stats[co] / cnt;
  float var = stats[256 + co] / cnt - mean * mean;
  float sc = gamma[co] * rsqrtf(var + 1e-5f);
  float sh = beta[co] - mean * sc;
  float4 v = ((float4*)y)[idx];
  v.x = fmaxf(v.x * sc + sh, 0.f);
  v.y = fmaxf(v.y * sc + sh, 0.f);
  v.z = fmaxf(v.z * sc + sh, 0.f);
  v.w = fmaxf(v.w * sc + sh, 0.f);
  ((float4*)y)[idx] = v;
}

extern "C" void kernel_launch(void* const* d_in, const int* in_sizes, int n_in,
                              void* d_out, int out_size, void* d_ws, size_t ws_size,
                              hipStream_t stream) {
  const float* x     = (const float*)d_in[0];
  const float* w     = (const float*)d_in[1];
  const float* gamma = (const float*)d_in[2];
  const float* beta  = (const float*)d_in[3];
  const int*   perm  = (const int*)d_in[4];
  float* out = (float*)d_out;
  char* ws = (char*)d_ws;

  unsigned short* xp = (unsigned short*)ws;
  unsigned short* wt = (unsigned short*)(ws + XP_BYTES);
  int* inv           = (int*)(ws + XP_BYTES + WT_BYTES);
  float* stats       = (float*)(ws + XP_BYTES + WT_BYTES + INV_BYTES);
  unsigned short* y  = (unsigned short*)(ws + WS_MIN);
  bool ymode = ws_size >= (size_t)WS_MIN + Y_BYTES;

  hipFuncSetAttribute(reinterpret_cast<const void*>(conv8_kernel<1>),
                      hipFuncAttributeMaxDynamicSharedMemorySize, 131072);
  hipFuncSetAttribute(reinterpret_cast<const void*>(conv8_kernel<0>),
                      hipFuncAttributeMaxDynamicSharedMemorySize, 131072);

  wcvt_kernel<<<1152, 256, 0, stream>>>(w, wt, perm, inv, stats);
  pad_perm_kernel<<<N_IMG * 49, 256, 0, stream>>>(x, inv, xp);
  if (ymode) {
    conv8_kernel<1><<<392, 512, 131072, stream>>>(xp, wt, y, out, stats);
    bnrelu1_kernel<<<COUT * (PXTOT / 8) / 256, 256, 0, stream>>>(y, stats, gamma, beta, out);
  } else {
    conv8_kernel<0><<<392, 512, 131072, stream>>>(xp, wt, (unsigned short*)out, out, stats);
    bnrelu0_kernel<<<N_IMG * COUT * HW / 4 / 256, 256, 0, stream>>>(out, stats, gamma, beta);
  }
}